// Round 8
// baseline (2090.206 us; speedup 1.0000x reference)
//
#include <hip/hip_runtime.h>
#include <cstdint>

#define TT 256
#define BB 8
#define NE 64
#define HH 512
#define VOCAB 32000
#define G4 2048
#define RS 32064          // out0 row stride (V + NE)
#define MROWS 2048        // B*T
#define SCALE 0.044194173824159216f  // 1/sqrt(512)

typedef _Float16 h2 __attribute__((ext_vector_type(2)));
typedef _Float16 h8 __attribute__((ext_vector_type(8)));
typedef float f4 __attribute__((ext_vector_type(4)));
typedef unsigned long long u64;

__device__ inline float sigf(float x){ return 1.f/(1.f+__expf(-x)); }

// agent-scope 64-bit payload words: hi32 = epoch, lo32 = f32 bits (single-copy atomic)
__device__ inline u64 g64load(const u64* p){
  return __hip_atomic_load((u64*)p, __ATOMIC_RELAXED, __HIP_MEMORY_SCOPE_AGENT);
}
__device__ inline void g64store(u64* p, u64 v){
  __hip_atomic_store(p, v, __ATOMIC_RELAXED, __HIP_MEMORY_SCOPE_AGENT);
}

// async global->LDS 16B: per-lane global addr, wave-uniform LDS base + lane*16
__device__ __forceinline__ void cp16(const _Float16* g, _Float16* l) {
  __builtin_amdgcn_global_load_lds(
      (__attribute__((address_space(1))) void*)(g),
      (__attribute__((address_space(3))) void*)(l), 16, 0, 0);
}

// ---------------- fused weight casts (descriptor table, one launch) ----------------
struct CDesc { const float* src; _Float16* dst; int total, sld, soff, dld, doff, cs, lo, tr; float mul; };
struct CPack { CDesc d[10]; int boff[11]; };

__global__ __launch_bounds__(256) void castall_k(CPack p)
{
  int blk = blockIdx.x;
  int di = 0;
  while (blk >= p.boff[di+1]) di++;
  CDesc d = p.d[di];
  int i = (blk - p.boff[di])*256 + threadIdx.x;
  if (i >= d.total) return;
  int c = i & ((1<<d.cs)-1);
  int r = i >> d.cs;
  float x = d.src[(long)r*d.sld + d.soff + c] * d.mul;
  _Float16 h = (_Float16)x;
  if (d.lo) h = (_Float16)(x - (float)h);
  if (d.tr) d.dst[(long)c*d.dld + d.doff + r] = h;
  else      d.dst[(long)r*d.dld + d.doff + c] = h;
}

// ---------------- single cast (f32 -> f16, hi or lo residual, optional scale) ----------------
__global__ __launch_bounds__(256) void cast_k(const float* __restrict__ src, _Float16* __restrict__ dst,
    int total, int src_ld, int src_off, int dst_ld, int dst_off, int cshift, int lo, float mul, int tr)
{
  int i = blockIdx.x*256 + threadIdx.x;
  if (i >= total) return;
  int c = i & ((1<<cshift)-1);
  int r = i >> cshift;
  float x = src[(long)r*src_ld + src_off + c] * mul;
  _Float16 h = (_Float16)x;
  if (lo) h = (_Float16)(x - (float)h);
  if (tr) dst[(long)c*dst_ld + dst_off + r] = h;
  else    dst[(long)r*dst_ld + dst_off + c] = h;
}

__global__ __launch_bounds__(256) void embgather_k(const float* __restrict__ emb,
    const int* __restrict__ outp, _Float16* __restrict__ dst)
{
  int i = blockIdx.x*256 + threadIdx.x;   // < 2048*512, rows m = t*8+b
  int k = i & 511; int m = i >> 9;
  int t = m >> 3, b = m & 7;
  int tok = outp[b*TT + t];
  dst[i] = (_Float16)emb[(long)tok*HH + k];
}

// prep: bias sum; hx(-1) = mean(ents) epoch-0 payload words; S buffer zero
__global__ __launch_bounds__(256) void prep_k(const float* __restrict__ b_ih, const float* __restrict__ b_hh,
    const float* __restrict__ ents, float* bsum, u64* hxe, u64* Se)
{
  int i = blockIdx.x*256 + threadIdx.x;   // grid 16 -> 4096 threads
  if (i < G4) bsum[i] = b_ih[i] + b_hh[i];
  if (i < BB*HH) {
    int b = i >> 9, j = i & 511;
    float s = 0.f;
    for (int n = 0; n < NE; n++) s += ents[(size_t)((b<<6)+n)*HH + j];
    s *= (1.0f/NE);
    hxe[i] = (u64)__float_as_uint(s);     // epoch 0
  }
  if (i < BB*256) Se[i] = 0ull;
}

// build block-diagonal-expanded V (f16), both row layouts
__global__ __launch_bounds__(256) void vblk_k(const float* __restrict__ Vb,
    _Float16* __restrict__ VblkS, _Float16* __restrict__ VblkT)
{
  int i = blockIdx.x*256 + threadIdx.x;   // < 8*512*256 = 1,048,576
  int he = i & 255, d = (i >> 8) & 511, b = i >> 17;
  _Float16 v = (_Float16)0.f;
  if ((he >> 6) == (d >> 7)) v = (_Float16)Vb[(((long)((b<<6)|(he&63)))<<9) + d];
  VblkT[(((long)((b<<9)|d))<<8) + he] = v;
  VblkS[(((long)((b<<8)|he))<<9) + d] = v;
}

// ---------------- f16 MFMA GEMM (m97 structure): C = A[M,K] * B[N,K]^T (+bias) ----------------
// global_load_lds width-16 staging into linear [128][32] LDS; 2-barrier K-loop.
// lda/ldb/ldc explicit; optional batch via blockIdx.z with element strides sA/sB/sC.
__global__ __launch_bounds__(256) void gemm_k(const _Float16* __restrict__ A, const _Float16* __restrict__ Bm,
    float* __restrict__ C, const float* __restrict__ bias,
    int M, int N, int K, int lda, int ldb, int ldc, int accum, long sA, long sB, long sC)
{
  __shared__ __align__(16) _Float16 At[128*32];   // 8KB linear, row stride 32 f16
  __shared__ __align__(16) _Float16 Bt[128*32];
  int z = blockIdx.z;
  A  += (long)z * sA;  Bm += (long)z * sB;  C += (long)z * sC;
  int tid = threadIdx.x;
  int n0 = blockIdx.x * 128, m0 = blockIdx.y * 128;
  int wave = tid >> 6, lane = tid & 63;
  int mw = (wave & 1) << 6, nw = (wave >> 1) << 6;
  // staging: issue j of wave w covers LDS bytes (2w+j)*1024 + lane*16
  //   = row (2w+j)*16 + lane/4, col f16 (lane&3)*8
  int srow = (wave << 5) + (lane >> 2);
  int scol = (lane & 3) << 3;
  const _Float16* Ag0 = A + (long)(m0 + srow)*lda + scol;
  const _Float16* Ag1 = Ag0 + (long)16*lda;
  const _Float16* Bg0 = Bm + (long)(n0 + srow)*ldb + scol;
  const _Float16* Bg1 = Bg0 + (long)16*ldb;
  _Float16* Ald = At + (wave << 10);       // f16 idx: wave*1024 (byte 2048w)
  _Float16* Bld = Bt + (wave << 10);
  f4 acc[4][4] = {};
  int rr = lane & 15, kq = (lane >> 4) << 3;
  for (int kt = 0; kt < K; kt += 32) {
    __syncthreads();                       // previous tile fully consumed
    cp16(Ag0 + kt, Ald);
    cp16(Ag1 + kt, Ald + 512);
    cp16(Bg0 + kt, Bld);
    cp16(Bg1 + kt, Bld + 512);
    __syncthreads();                       // compiler drains vmcnt before barrier
    h8 af[4], bf[4];
    #pragma unroll
    for (int mt=0;mt<4;mt++) af[mt] = *(const h8*)&At[((mw + mt*16 + rr) << 5) + kq];
    #pragma unroll
    for (int nt=0;nt<4;nt++) bf[nt] = *(const h8*)&Bt[((nw + nt*16 + rr) << 5) + kq];
    #pragma unroll
    for (int mt=0;mt<4;mt++)
      #pragma unroll
      for (int nt=0;nt<4;nt++)
        acc[mt][nt] = __builtin_amdgcn_mfma_f32_16x16x32_f16(af[mt], bf[nt], acc[mt][nt], 0, 0, 0);
  }
  int cc = lane & 15, rq = (lane >> 4) << 2;
  #pragma unroll
  for (int nt=0;nt<4;nt++) {
    int col = n0 + nw + nt*16 + cc;
    float bv = bias ? bias[col] : 0.f;
    #pragma unroll
    for (int mt=0;mt<4;mt++) {
      int row0 = m0 + mw + mt*16 + rq;
      #pragma unroll
      for (int r=0;r<4;r++) {
        long idx = (long)(row0 + r)*ldc + col;
        float v = acc[mt][nt][r] + bv;
        if (accum) C[idx] += v; else C[idx] = v;
      }
    }
  }
}

// ---------------- batch-local persistent RNN (unchanged from r7) ----------------
__global__ __launch_bounds__(512, 1) void rnn_k(
    const float* __restrict__ gates_pre, const _Float16* __restrict__ Whh16,
    const float* __restrict__ Mh, const float* __restrict__ WVall,
    const int* __restrict__ entlens,
    u64* hxe, u64* Se, _Float16* Pg, _Float16* l_h, _Float16* l_lo)
{
  __shared__ __align__(16) _Float16 Wl2[32768];   // 64KB  [8c][64r][8sl][8] Whh tiles
  __shared__ __align__(16) _Float16 WVl2[16384];  // 32KB  [32c][64r][8] WV tiles
  __shared__ __align__(16) float    Ml2[8][512];  // 16KB  score rows (linear)
  __shared__ __align__(16) float    hxs[512];     // staged hx f32
  __shared__ __align__(16) _Float16 hxh[512];     // staged hx f16
  __shared__ __align__(16) _Float16 ph[256];      // p f16 (per-head segments)
  __shared__ float part[4][64];                   // WVp quarter partials
  __shared__ float gsum[64];                      // hh-matvec row sums
  __shared__ float gpl[64];                       // gpre prefetch

  const int tid = threadIdx.x, wg = blockIdx.x;
  const int b = wg >> 5, wgl = wg & 31, u_off = wgl << 4;
  const int lane = tid & 63, wv = tid >> 6;
  const int el = entlens[b];
  const int h_own = wgl >> 3, e_base = (wgl & 7) << 3;  // score rows [8wgl,8wgl+8)
  u64* hxb = hxe + ((long)b << 9);
  u64* Sb  = Se  + ((long)b << 8);

  // ---- one-time: weights -> LDS (tiled) ----
  for (int i = tid; i < 4096; i += 512) {          // Whh h8 chunks -> [c][r][sl], k8c = c*8+sl
    int r = i >> 6, k8c = i & 63;
    int c = k8c >> 3, sl = k8c & 7;
    int grow = ((r >> 4) << 9) + u_off + (r & 15); // gate*512 + 16wgl + u
    *(h8*)&Wl2[((((c << 6) + r) << 3) + sl) << 3] =
        *(const h8*)(Whh16 + ((long)grow << 9) + (k8c << 3));
  }
  for (int i = tid; i < 4096; i += 512) {          // M rows linear f32
    int r = i >> 9, e = i & 511;
    Ml2[r][e] = Mh[((long)h_own << 18) + (((long)((b << 6) + e_base + r)) << 9) + e];
  }
  for (int i = tid; i < 16384; i += 512) {         // WV f32 -> f16 tiled [c][r][8]
    int r = i >> 8, cj = i & 255, c = cj >> 3, j = cj & 7;
    int grow = ((r >> 4) << 9) + u_off + (r & 15);
    WVl2[((((c << 6) + r) << 3) + j)] = (_Float16)WVall[((long)grow << 11) + (b << 8) + cj];
  }
  // ---- stage hx(-1) (epoch 0 from prep, same stream: plain load) ----
  if (tid < 256) {
    u64 w0 = g64load(hxb + 2*tid), w1 = g64load(hxb + 2*tid + 1);
    float f0 = __uint_as_float((unsigned)w0), f1 = __uint_as_float((unsigned)w1);
    hxs[2*tid] = f0; hxs[2*tid+1] = f1;
    hxh[2*tid] = (_Float16)f0; hxh[2*tid+1] = (_Float16)f1;
  }
  __syncthreads();
  float cx = 0.f;
  if (wv == 0 && lane < 16) cx = hxs[u_off + lane];   // cx0 = hx0

  for (int it = 0; it < TT; it++) {
    const unsigned set = (unsigned)(it + 1);
    // ---- A: own S row = hxs . Ml2[wv], stride-64 interleave (bank-free), post tag ----
    {
      float sp = 0.f;
      #pragma unroll
      for (int j = 0; j < 8; j++) sp += hxs[(j << 6) + lane] * Ml2[wv][(j << 6) + lane];
      #pragma unroll
      for (int off = 32; off; off >>= 1) sp += __shfl_xor(sp, off);
      if (lane == 0)
        g64store(Sb + (h_own << 6) + e_base + wv, ((u64)set << 32) | (u64)__float_as_uint(sp));
    }
    if (tid < 64) {   // gpre prefetch
      int col = ((tid >> 4) << 9) + u_off + (tid & 15);
      gpl[tid] = gates_pre[((long)((it << 3) + b) << 11) + col];
    }
    // ---- B: hh matvec; thread (r,sl) handles k-chunks c*8+sl; both reads bank-free ----
    {
      int sl = tid & 7;
      float s = 0.f;
      #pragma unroll
      for (int c = 0; c < 8; c++) {
        union { h8 v; h2 p[4]; } a_, w_;
        a_.v = *(const h8*)&hxh[(c << 6) + (sl << 3)];
        w_.v = *(const h8*)&Wl2[((c << 9) + tid) << 3];
        #pragma unroll
        for (int p = 0; p < 4; p++) s = __builtin_amdgcn_fdot2(a_.p[p], w_.p[p], s, false);
      }
      s += __shfl_xor(s, 1); s += __shfl_xor(s, 2); s += __shfl_xor(s, 4);
      if (sl == 0) gsum[tid >> 3] = s;
    }
    // ---- D1 (waves 0-3): poll S head wv (1 word/lane), softmax, quarter WVp ----
    if (wv < 4) {
      u64 sv = g64load(Sb + (wv << 6) + lane);
      while ((unsigned)(sv >> 32) < set) { __builtin_amdgcn_s_sleep(1); sv = g64load(Sb + (wv << 6) + lane); }
      if (it > 0) {
        float x = __uint_as_float((unsigned)sv);
        if (lane > el) x = -1e30f;
        float mx = x;
        #pragma unroll
        for (int off = 32; off; off >>= 1) mx = fmaxf(mx, __shfl_xor(mx, off));
        float e = __expf(x - mx), sm = e;
        #pragma unroll
        for (int off = 32; off; off >>= 1) sm += __shfl_xor(sm, off);
        float p = e / sm;
        _Float16 p16 = (_Float16)p;
        ph[(wv << 6) + lane] = p16;
        float s = 0.f;           // partial WVp over entities [64wv,64wv+64), row = lane
        #pragma unroll
        for (int cc = 0; cc < 8; cc++) {
          int c = (wv << 3) + cc;
          union { h8 v; h2 p[4]; } pv, wv_;
          pv.v  = *(const h8*)&ph[(wv << 6) + (cc << 3)];
          wv_.v = *(const h8*)&WVl2[(((c << 6) + lane) << 3)];
          #pragma unroll
          for (int p2 = 0; p2 < 4; p2++) s = __builtin_amdgcn_fdot2(pv.p[p2], wv_.p[p2], s, false);
        }
        part[wv][lane] = s;
        Pg[((long)((b << 8) + (it - 1)) << 8) + (wv << 6) + lane] = p16;
      }
    }
    __syncthreads();   // C2: gsum + part visible; hxs/hxh free after this
    // ---- D2 (wave0): sum partials + cell + hx post ----
    if (wv == 0) {
      float wvp = (it > 0) ? (part[0][lane] + part[1][lane] + part[2][lane] + part[3][lane]) : 0.f;
      float gv = gpl[lane] + gsum[lane] + wvp;
      float gi = __shfl(gv, lane & 15);
      float gf = __shfl(gv, 16 + (lane & 15));
      float gg = __shfl(gv, 32 + (lane & 15));
      float go = __shfl(gv, 48 + (lane & 15));
      if (lane < 16) {
        float c_ = sigf(gf)*cx + sigf(gi)*tanhf(gg);
        cx = c_;
        float h = sigf(go)*tanhf(c_);
        int j = u_off + lane;
        g64store(hxb + j, ((u64)set << 32) | (u64)__float_as_uint(h));
        _Float16 hh_ = (_Float16)h;
        long li = ((long)((b << 8) + it)) << 10;
        l_h[li + j]  = hh_;
        l_lo[li + j] = (_Float16)(h - (float)hh_);
      }
    }
    // ---- F: poll hx(it) tag it+1, restage ----
    if (tid < 256) {
      u64 w0 = g64load(hxb + 2*tid), w1 = g64load(hxb + 2*tid + 1);
      while ((unsigned)(w0 >> 32) < set) { __builtin_amdgcn_s_sleep(1); w0 = g64load(hxb + 2*tid); }
      while ((unsigned)(w1 >> 32) < set) { __builtin_amdgcn_s_sleep(1); w1 = g64load(hxb + 2*tid + 1); }
      float f0 = __uint_as_float((unsigned)w0), f1 = __uint_as_float((unsigned)w1);
      hxs[2*tid] = f0; hxs[2*tid+1] = f1;
      hxh[2*tid] = (_Float16)f0; hxh[2*tid+1] = (_Float16)f1;
    }
    __syncthreads();   // G
  }
  // ---- epilogue: p(255) from hx(255), tag 257 ----
  {
    float sp = 0.f;
    #pragma unroll
    for (int j = 0; j < 8; j++) sp += hxs[(j << 6) + lane] * Ml2[wv][(j << 6) + lane];
    #pragma unroll
    for (int off = 32; off; off >>= 1) sp += __shfl_xor(sp, off);
    if (lane == 0)
      g64store(Sb + (h_own << 6) + e_base + wv, ((u64)257u << 32) | (u64)__float_as_uint(sp));
    if (wv < 4) {
      u64 sv = g64load(Sb + (wv << 6) + lane);
      while ((unsigned)(sv >> 32) < 257u) { __builtin_amdgcn_s_sleep(1); sv = g64load(Sb + (wv << 6) + lane); }
      float x = __uint_as_float((unsigned)sv);
      if (lane > el) x = -1e30f;
      float mx = x;
      #pragma unroll
      for (int off = 32; off; off >>= 1) mx = fmaxf(mx, __shfl_xor(mx, off));
      float e = __expf(x - mx), sm = e;
      #pragma unroll
      for (int off = 32; off; off >>= 1) sm += __shfl_xor(sm, off);
      Pg[((long)((b << 8) + 255) << 8) + (wv << 6) + lane] = (_Float16)(e / sm);
    }
  }
}

// ---------------- fused stats+finalize: one read + one write of the V row ----------------
__global__ __launch_bounds__(256) void statsfin_k(float* __restrict__ out,
    const _Float16* __restrict__ l_h, const float* __restrict__ swW, const float* __restrict__ swb,
    const float* __restrict__ dec, const float* __restrict__ ents, const int* __restrict__ entlens)
{
  __shared__ __align__(16) float rowb[VOCAB];   // 128 KB row buffer
  __shared__ float dl[512];
  __shared__ float red[3][4];
  __shared__ float bc[3];                       // MX, inv, s
  int m = blockIdx.x, tid = threadIdx.x;
  int b = m >> 8;
  float* row = out + (long)m*RS;
  // pass1: global -> LDS, thread max; also dl and switch-gate dot
  float mx = -1e30f;
  for (int c4 = tid; c4 < 8000; c4 += 256) {
    f4 v = *(const f4*)(row + ((long)c4 << 2));
    *(f4*)&rowb[c4 << 2] = v;
    mx = fmaxf(mx, fmaxf(fmaxf(v[0], v[1]), fmaxf(v[2], v[3])));
  }
  for (int i = tid; i < 512; i += 256) dl[i] = dec[((long)m << 9) + i];
  float sd = 0.f;
  const _Float16* lr_ = l_h + ((long)m << 10);
  for (int k = tid; k < 1024; k += 256) sd += (float)lr_[k] * swW[k];
  int wv = tid >> 6;
  #pragma unroll
  for (int off = 32; off; off >>= 1) { mx = fmaxf(mx, __shfl_xor(mx, off)); sd += __shfl_xor(sd, off); }
  if ((tid & 63) == 0) { red[0][wv] = mx; red[1][wv] = sd; }
  __syncthreads();
  if (tid == 0) {
    bc[0] = fmaxf(fmaxf(red[0][0], red[0][1]), fmaxf(red[0][2], red[0][3]));
    float D_ = red[1][0] + red[1][1] + red[1][2] + red[1][3];
    bc[2] = 1.f/(1.f + __expf(-(D_ + swb[0])));
  }
  __syncthreads();
  float MX = bc[0];
  // pass2: exp + sum (store e back into rowb)
  float sm = 0.f;
  for (int c4 = tid; c4 < 8000; c4 += 256) {
    f4 v = *(const f4*)&rowb[c4 << 2];
    #pragma unroll
    for (int j = 0; j < 4; j++) v[j] = __expf(v[j] - MX);
    sm += v[0] + v[1] + v[2] + v[3];
    *(f4*)&rowb[c4 << 2] = v;
  }
  #pragma unroll
  for (int off = 32; off; off >>= 1) sm += __shfl_xor(sm, off);
  if ((tid & 63) == 0) red[2][wv] = sm;
  __syncthreads();
  if (tid == 0) bc[1] = 1.f/(red[2][0] + red[2][1] + red[2][2] + red[2][3]);
  __syncthreads();
  float s = bc[2], inv = bc[1];
  // pointer-z over entities
  if (tid < 64) {
    int n = tid;
    const float* ep = ents + (((long)((b << 6) + n)) << 9);
    float uq = 0.f;
    for (int k = 0; k < 512; k += 4)
      uq += dl[k]*ep[k] + dl[k+1]*ep[k+1] + dl[k+2]*ep[k+2] + dl[k+3]*ep[k+3];
    if (n > entlens[b]) uq = -1e30f;
    float mxz = uq;
    #pragma unroll
    for (int off = 32; off; off >>= 1) mxz = fmaxf(mxz, __shfl_xor(mxz, off));
    float e = __expf(uq - mxz);
    float sum = e;
    #pragma unroll
    for (int off = 32; off; off >>= 1) sum += __shfl_xor(sum, off);
    float z = (e/sum) * (1.f - s);
    out[(long)m*RS + VOCAB + n] = __logf(z + 1e-6f);
    out[(long)MROWS*RS + ((long)m << 6) + n] = z;     // output 1
  }
  // transform + write
  for (int c4 = tid; c4 < 8000; c4 += 256) {
    f4 v = *(const f4*)&rowb[c4 << 2];
    #pragma unroll
    for (int j = 0; j < 4; j++) v[j] = __logf(v[j]*inv*s + 1e-6f);
    *(f4*)(row + ((long)c4 << 2)) = v;
  }
}

// ---------------- launch ----------------
extern "C" void kernel_launch(void* const* d_in, const int* in_sizes, int n_in,
                              void* d_out, int out_size, void* d_ws, size_t ws_size,
                              hipStream_t stream)
{
  const int*   outp    = (const int*)d_in[0];
  const float* ents    = (const float*)d_in[1];
  const int*   entlens = (const int*)d_in[2];
  const float* emb     = (const float*)d_in[3];
  const float* W_ih    = (const float*)d_in[4];
  const float* W_hh    = (const float*)d_in[5];
  const float* b_ih    = (const float*)d_in[6];
  const float* b_hh    = (const float*)d_in[7];
  const float* Wq      = (const float*)d_in[8];
  const float* Wk      = (const float*)d_in[9];
  const float* Wv      = (const float*)d_in[10];
  const float* out_W   = (const float*)d_in[11];
  const float* out_b   = (const float*)d_in[12];
  const float* sw_W    = (const float*)d_in[13];
  const float* sw_b    = (const float*)d_in[14];
  const float* mattn_W = (const float*)d_in[15];
  const float* mattn_b = (const float*)d_in[16];
  float* out = (float*)d_out;
  (void)in_sizes; (void)n_in; (void)out_size; (void)ws_size;

  char* w = (char*)d_ws;
  size_t off = 0;
  auto alloc = [&](size_t bytes) -> char* {
    char* p = w + off; off += bytes; off = (off + 255) & ~(size_t)255; return p;
  };
  _Float16* outW_h = (_Float16*)alloc((size_t)VOCAB*1024*2);   // 65.5 MB
  _Float16* l_h    = (_Float16*)alloc((size_t)MROWS*1024*2);
  _Float16* l_lo   = (_Float16*)alloc((size_t)MROWS*1024*2);
  float*    gpre   = (float*)alloc((size_t)MROWS*2048*4);      // 16 MB (aliased by Af post-rnn)
  _Float16* Wihk_h = (_Float16*)alloc((size_t)2048*512*2);
  _Float16* Wiha16 = (_Float16*)alloc((size_t)2048*512*2);
  _Float16* Whh16  = (_Float16*)alloc((size_t)2048*512*2);
  _Float16* emb_h  = (_Float16*)alloc((size_t)2048*512*2);
  _Float16* ents_h = (_Float16*)alloc((size_t)512*512*2);
  _Float16* Wk_h   = (_Float16*)alloc((size_t)512*512*2);      // adjacent to Wv_h (z-batch)
  _Float16* Wv_h   = (_Float16*)alloc((size_t)512*512*2);
  _Float16* WqT16  = (_Float16*)alloc((size_t)512*512*2);
  _Float16* mat_h  = (_Float16*)alloc((size_t)512*1024*2);
  _Float16* mat_lo = (_Float16*)alloc((size_t)512*1024*2);
  float*    Kb     = (float*)alloc((size_t)512*512*4);         // adjacent to Vb (z-batch)
  float*    Vb     = (float*)alloc((size_t)512*512*4);
  _Float16* Kb16   = (_Float16*)alloc((size_t)512*512*2);
  float*    Mh     = (float*)alloc((size_t)4*512*512*4);       // 4 MB
  _Float16* VblkS  = (_Float16*)alloc((size_t)2048*512*2);     // 2 MB
  _Float16* VblkT  = (_Float16*)alloc((size_t)8*512*256*2);    // 2 MB
  float*    WVall  = (float*)alloc((size_t)2048*2048*4);       // 16 MB
  _Float16* Pg     = (_Float16*)alloc((size_t)8*256*256*2);    // 1 MB
  float*    dec    = (float*)alloc((size_t)MROWS*512*4);
  float*    bsum   = (float*)alloc(2048*4);
  u64*      hxe    = (u64*)alloc((size_t)4096*8);
  u64*      Se     = (u64*)alloc((size_t)2048*8);
  float*    Af     = gpre;   // alias: gpre dead after rnn_k; Af written by avP after

  auto gemm = [&](const _Float16* A, const _Float16* B, float* C, const float* bias,
                  int M, int N, int K, int lda, int ldb, int ldc, int accum,
                  int gx, int gy, int gz, long sA, long sB, long sC) {
    gemm_k<<<dim3(gx,gy,gz), 256, 0, stream>>>(A, B, C, bias, M, N, K, lda, ldb, ldc, accum, sA, sB, sC);
  };
  auto cast = [&](const float* s, _Float16* d, int total, int sld, int soff, int dld, int doff,
                  int cs, int lo, float mul, int tr) {
    cast_k<<<(total+255)/256, 256, 0, stream>>>(s, d, total, sld, soff, dld, doff, cs, lo, mul, tr);
  };

  // ---- all input-weight casts in one launch ----
  CPack cp;
  auto setd = [&](int i, const float* s, _Float16* d, int total, int sld, int soff, int dld, int doff,
                  int cs, int lo, int tr, float mul) {
    cp.d[i] = CDesc{ s, d, total, sld, soff, dld, doff, cs, lo, tr, mul };
  };
  setd(0, out_W,   outW_h, VOCAB*1024, 1024, 0,   1024, 0,   10, 0, 0, 1.f);
  setd(1, W_ih,    Wihk_h, 2048*512,   1024, 512, 512,  0,   9,  0, 0, 1.f);
  setd(2, W_ih,    Wiha16, 2048*512,   1024, 0,   512,  0,   9,  0, 0, 1.f);
  setd(3, W_hh,    Whh16,  2048*512,   512,  0,   512,  0,   9,  0, 0, 1.f);
  setd(4, Wq,      WqT16,  512*512,    512,  0,   512,  0,   9,  0, 1, 1.f);   // transposed
  setd(5, Wk,      Wk_h,   512*512,    512,  0,   512,  0,   9,  0, 0, 1.f);
  setd(6, Wv,      Wv_h,   512*512,    512,  0,   512,  0,   9,  0, 0, 1.f);
  setd(7, mattn_W, mat_h,  512*1024,   1024, 0,   1024, 0,   10, 0, 0, 1.f);
  setd(8, mattn_W, mat_lo, 512*1024,   1024, 0,   1024, 0,   10, 1, 0, 1.f);
  setd(9, ents,    ents_h, 512*512,    512,  0,   512,  0,   9,  0, 0, 1.f);
  cp.boff[0] = 0;
  for (int i = 0; i < 10; i++) cp.boff[i+1] = cp.boff[i] + (cp.d[i].total + 255)/256;
  castall_k<<<cp.boff[10], 256, 0, stream>>>(cp);

  embgather_k<<<4096, 256, 0, stream>>>(emb, outp, emb_h);
  prep_k<<<16, 256, 0, stream>>>(b_ih, b_hh, ents, bsum, hxe, Se);

  // K and V projections z-batched (Wk_h/Wv_h and Kb/Vb are exactly adjacent)
  gemm(ents_h, Wk_h, Kb, nullptr, 512, 512, 512, 512, 512, 512, 0,
       4, 4, 2, 0, (long)512*512, (long)512*512);
  gemm(emb_h, Wihk_h, gpre, bsum, 2048, 2048, 512, 512, 512, 2048, 0, 16, 16, 1, 0,0,0);

  cast(Kb, Kb16, 512*512, 512, 0, 512, 0, 9, 0, SCALE, 0);    // fold 1/sqrt(512) into K
  vblk_k<<<4096, 256, 0, stream>>>(Vb, VblkS, VblkT);

  // M_h = (K_h*s) @ Wq_h^T, 4 heads z-batched
  gemm(Kb16, WqT16, Mh, nullptr, 512, 512, 128, 512, 512, 512, 0,
       4, 4, 4, 128, 128, (long)512*512);
  gemm(Wiha16, VblkS, WVall, nullptr,                          // WV = W_ih_a @ Vblk^T
       2048, 2048, 512, 512, 512, 2048, 0, 16, 16, 1, 0,0,0);

  rnn_k<<<256, 512, 0, stream>>>(gpre, Whh16, Mh, WVall, entlens, hxe, Se, Pg, l_h, l_lo);

  // postpass: A[b] = P[b] @ Vblk[b]^T  (batched), then cast into l_h/l_lo a-part
  gemm(Pg, VblkT, Af, nullptr, 256, 512, 256, 256, 256, 512, 0,
       4, 2, 8, (long)256*256, (long)512*256, (long)256*512);
  cast(Af, l_h,  MROWS*512, 512, 0, 1024, 512, 9, 0, 1.f, 0);
  cast(Af, l_lo, MROWS*512, 512, 0, 1024, 512, 9, 1, 1.f, 0);

  gemm(l_h,  mat_h,  dec, mattn_b, 2048, 512,   1024, 1024, 1024, 512, 0, 4,  16, 1, 0,0,0);
  gemm(l_lo, mat_h,  dec, nullptr, 2048, 512,   1024, 1024, 1024, 512, 1, 4,  16, 1, 0,0,0);
  gemm(l_h,  mat_lo, dec, nullptr, 2048, 512,   1024, 1024, 1024, 512, 1, 4,  16, 1, 0,0,0);
  gemm(l_h,  outW_h, out, out_b,   2048, 32000, 1024, 1024, 1024, RS,  0, 250, 16, 1, 0,0,0);

  statsfin_k<<<2048, 256, 0, stream>>>(out, l_h, sw_W, sw_b, dec, ents, entlens);
}